// Round 21
// baseline (250.560 us; speedup 1.0000x reference)
//
#include <hip/hip_runtime.h>
#include <math.h>

#define BB 512
#define SS 1024
#define KK 128
#define VV 512
#define NC 8      // s-chunks per batch (2x oversubscription)
#define CH 128    // rows per chunk
#define KS 8      // K-split for MLP GEMMs (512 blocks = 2 blocks/CU)
#define QB 8      // batches per q-block

static constexpr float INV_SCALE = 0.088388347648318447f; // 1/sqrt(128)

typedef float nfloat4 __attribute__((ext_vector_type(4)));

__device__ __forceinline__ float4 ntload(const float4* p) {
    nfloat4 v = __builtin_nontemporal_load((const nfloat4*)p);
    return make_float4(v.x, v.y, v.z, v.w);
}

// ---------------- query kernel: q = hidden @ Wq.T + bq (coalesced, staged) ---
__global__ __launch_bounds__(256) void q_kernel(
    const float* __restrict__ hidden, const float* __restrict__ Wq,
    const float* __restrict__ bq, float* __restrict__ qout)
{
    __shared__ float hidb[QB][516];
    __shared__ float wqt[16][516];
    __shared__ float qp[16][QB][2];
    const int blk = blockIdx.x;
    const int t = threadIdx.x;
    const int b0 = blk * QB;

    for (int i = t; i < QB * 128; i += 256) {
        const int bl = i >> 7, c4 = i & 127;
        *(float4*)&hidb[bl][c4 * 4] =
            ((const float4*)(hidden + (size_t)(b0 + bl) * VV))[c4];
    }
    for (int k0 = 0; k0 < KK; k0 += 16) {
        __syncthreads();
        for (int i = t; i < 16 * 128; i += 256) {
            const int kl = i >> 7, c4 = i & 127;
            *(float4*)&wqt[kl][c4 * 4] =
                ((const float4*)(Wq + (size_t)(k0 + kl) * VV))[c4];
        }
        __syncthreads();
        {
            const int p = t & 127, half = t >> 7;
            const int kl = p >> 3, bl = p & 7;
            const float* wr = &wqt[kl][half * 256];
            const float* hr = &hidb[bl][half * 256];
            float acc = 0.f;
            #pragma unroll
            for (int j = 0; j < 64; ++j) {
                const float4 wv = *(const float4*)&wr[j * 4];
                const float4 hv = *(const float4*)&hr[j * 4];
                acc += wv.x * hv.x + wv.y * hv.y + wv.z * hv.z + wv.w * hv.w;
            }
            qp[kl][bl][half] = acc;
        }
        __syncthreads();
        if (t < 128) {
            const int kl = t >> 3, bl = t & 7;
            qout[(size_t)(b0 + bl) * KK + k0 + kl] =
                qp[kl][bl][0] + qp[kl][bl][1] + bq[k0 + kl];
        }
    }
}

// ---------------- attention chunk (NC=8, CH=128, nt loads) -------------------
__global__ __launch_bounds__(256) void attn_chunk_kernel(
    const float* __restrict__ keys, const float* __restrict__ values,
    const float* __restrict__ keyv, const float* __restrict__ valv,
    const float* __restrict__ q,
    const int* __restrict__ write_ptr, const int* __restrict__ filled,
    float* __restrict__ ml, float* __restrict__ accp)
{
    __shared__ __align__(16) float qs[KK];
    __shared__ __align__(16) float p[CH];
    __shared__ __align__(16) float red[4];
    __shared__ __align__(16) float4 pvp[VV / 4];

    const int bc = blockIdx.x;
    const int b = bc >> 3;
    const int c = bc & 7;
    const int t = threadIdx.x;
    const int wave = t >> 6, lane = t & 63;

    int f = filled[b] + 1; if (f > SS) f = SS;
    const int sbeg = c * CH;
    int n = f - sbeg; if (n > CH) n = CH;

    float* mlrow = ml + ((size_t)b * NC + c) * 2;
    float* arow  = accp + ((size_t)b * NC + c) * VV;

    if (n <= 0) {
        if (t == 0) { mlrow[0] = -INFINITY; mlrow[1] = 0.f; }
        return;
    }

    if (t < KK / 4) ((float4*)qs)[t] = ((const float4*)(q + (size_t)b * KK))[t];
    __syncthreads();

    const int sub = lane & 31, rsel = lane >> 5;
    const int srow = wave * 2 + rsel;  // 0..7
    const float4 q4 = ((const float4*)qs)[sub];
    const float* kb = keys + ((size_t)b * SS + sbeg) * KK;
    const float* kw = keyv + (size_t)b * KK;
    const int wpl = write_ptr[b] - sbeg;

    const int nmain = n & ~31;
    for (int s0 = 0; s0 < nmain; s0 += 32) {
        float4 kv[4];
        #pragma unroll
        for (int u = 0; u < 4; ++u) {
            const int s = s0 + u * 8 + srow;
            const float* kr = (s == wpl) ? kw : (kb + (size_t)s * KK);
            kv[u] = ntload(((const float4*)kr) + sub);
        }
        #pragma unroll
        for (int u = 0; u < 4; ++u) {
            float prt = kv[u].x * q4.x + kv[u].y * q4.y
                      + kv[u].z * q4.z + kv[u].w * q4.w;
            prt += __shfl_xor(prt, 16);
            prt += __shfl_xor(prt, 8);
            prt += __shfl_xor(prt, 4);
            prt += __shfl_xor(prt, 2);
            prt += __shfl_xor(prt, 1);
            if (sub == 0) p[s0 + u * 8 + srow] = prt * INV_SCALE;
        }
    }
    for (int s = nmain + srow; s < n; s += 8) {
        const float* kr = (s == wpl) ? kw : (kb + (size_t)s * KK);
        const float4 kv = ntload(((const float4*)kr) + sub);
        float prt = kv.x * q4.x + kv.y * q4.y + kv.z * q4.z + kv.w * q4.w;
        prt += __shfl_xor(prt, 16);
        prt += __shfl_xor(prt, 8);
        prt += __shfl_xor(prt, 4);
        prt += __shfl_xor(prt, 2);
        prt += __shfl_xor(prt, 1);
        if (sub == 0) p[s] = prt * INV_SCALE;
    }
    __syncthreads();

    float lmax = -INFINITY;
    for (int i = t; i < n; i += 256) lmax = fmaxf(lmax, p[i]);
    lmax = fmaxf(lmax, __shfl_xor(lmax, 32));
    lmax = fmaxf(lmax, __shfl_xor(lmax, 16));
    lmax = fmaxf(lmax, __shfl_xor(lmax, 8));
    lmax = fmaxf(lmax, __shfl_xor(lmax, 4));
    lmax = fmaxf(lmax, __shfl_xor(lmax, 2));
    lmax = fmaxf(lmax, __shfl_xor(lmax, 1));
    if (lane == 0) red[wave] = lmax;
    __syncthreads();
    const float m = fmaxf(fmaxf(red[0], red[1]), fmaxf(red[2], red[3]));
    float lsum = 0.f;
    for (int i = t; i < n; i += 256) {
        const float e = __expf(p[i] - m);
        p[i] = e;
        lsum += e;
    }
    lsum += __shfl_xor(lsum, 32);
    lsum += __shfl_xor(lsum, 16);
    lsum += __shfl_xor(lsum, 8);
    lsum += __shfl_xor(lsum, 4);
    lsum += __shfl_xor(lsum, 2);
    lsum += __shfl_xor(lsum, 1);
    __syncthreads();
    if (lane == 0) red[wave] = lsum;
    __syncthreads();
    const float l = red[0] + red[1] + red[2] + red[3];

    const int col4 = t & 127, stream = t >> 7;
    const float4* vb = (const float4*)(values + ((size_t)b * SS + sbeg) * VV);
    const float4* vw = (const float4*)(valv + (size_t)b * VV);
    float4 acc = make_float4(0.f, 0.f, 0.f, 0.f);
    const int nm2 = n & ~15;
    for (int s0 = 0; s0 < nm2; s0 += 16) {
        float4 v[8]; float ps[8];
        #pragma unroll
        for (int u = 0; u < 8; ++u) {
            const int s = s0 + u * 2 + stream;
            const float4* vr = (s == wpl) ? vw : (vb + (size_t)s * (VV / 4));
            v[u] = ntload(vr + col4);
            ps[u] = p[s];
        }
        #pragma unroll
        for (int u = 0; u < 8; ++u) {
            acc.x += ps[u] * v[u].x;
            acc.y += ps[u] * v[u].y;
            acc.z += ps[u] * v[u].z;
            acc.w += ps[u] * v[u].w;
        }
    }
    for (int s = nm2 + stream; s < n; s += 2) {
        const float4* vr = (s == wpl) ? vw : (vb + (size_t)s * (VV / 4));
        const float4 v = ntload(vr + col4);
        const float psv = p[s];
        acc.x += psv * v.x;
        acc.y += psv * v.y;
        acc.z += psv * v.z;
        acc.w += psv * v.w;
    }
    if (stream == 1) pvp[col4] = acc;
    __syncthreads();
    if (stream == 0) {
        const float4 o = pvp[col4];
        ((float4*)arow)[col4] = make_float4(acc.x + o.x, acc.y + o.y,
                                            acc.z + o.z, acc.w + o.w);
    }
    if (t == 0) { mlrow[0] = m; mlrow[1] = l; }
}

// ---------------- combine -> hcat = [hidden | retrieved]; also out = bo ------
__global__ __launch_bounds__(128) void combine_kernel(
    const float* __restrict__ hidden, const float* __restrict__ ml,
    const float* __restrict__ accp, float* __restrict__ hcat,
    const float* __restrict__ bo, float* __restrict__ out)
{
    const int b = blockIdx.x, t = threadIdx.x;
    const float* mlb = ml + (size_t)b * NC * 2;
    float mv[NC], lv[NC];
    #pragma unroll
    for (int c = 0; c < NC; ++c) { mv[c] = mlb[2 * c]; lv[c] = mlb[2 * c + 1]; }
    float ms = mv[0];
    #pragma unroll
    for (int c = 1; c < NC; ++c) ms = fmaxf(ms, mv[c]);
    float w[NC], denom = 0.f;
    #pragma unroll
    for (int c = 0; c < NC; ++c) { w[c] = __expf(mv[c] - ms); denom += w[c] * lv[c]; }
    const float invd = 1.f / denom;
    float4 r = make_float4(0.f, 0.f, 0.f, 0.f);
    for (int c = 0; c < NC; ++c) {
        if (lv[c] != 0.f) {
            const float4 x = ((const float4*)(accp + ((size_t)b * NC + c) * VV))[t];
            r.x += w[c] * x.x; r.y += w[c] * x.y;
            r.z += w[c] * x.z; r.w += w[c] * x.w;
        }
    }
    r.x *= invd; r.y *= invd; r.z *= invd; r.w *= invd;
    float4* hc = (float4*)(hcat + (size_t)b * 2 * VV);
    hc[t] = ((const float4*)(hidden + (size_t)b * VV))[t];
    hc[VV / 4 + t] = r;
    // pre-init out with bias (gemm3 atomicAdds partials on top)
    ((float4*)(out + (size_t)b * VV))[t] = ((const float4*)bo)[t];
}

// ---------------- K-split GEMM, double-buffered LDS staging ------------------
// W row-major [512][K], transposed during staging. Tile 64x64, 4x4 micro,
// BK=16, grid = 64 x KS = 512 blocks (2/CU).
// mode 0: A_eff = Agl (hcat) -> part[ks]
// mode 1: A_eff = silu(sum_KS prev + bias) -> part[ks]
// mode 2: A_eff = hc[:,:512] + hc[:,512:]*sigmoid(sum_KS prev + bias);
//         epilogue atomicAdds into dst (out pre-initialized with bo)
__global__ __launch_bounds__(256) void gemm_ks_kernel(
    const float* __restrict__ Agl, int K, const float* __restrict__ W,
    const float* __restrict__ prev, const float* __restrict__ bias,
    const float* __restrict__ hc, float* __restrict__ dst, int mode)
{
    __shared__ __align__(16) float As[2][16][68];
    __shared__ __align__(16) float Bs[2][16][68];
    const int bx = blockIdx.x;
    const int mt = bx & 7, nt = (bx >> 3) & 7, ks = bx >> 6;
    const int kseg = K >> 3;               // K / KS
    const int kbeg = ks * kseg, kend = kbeg + kseg;
    const int t = threadIdx.x;
    const int tx = t & 15, ty = t >> 4;
    const int m0 = mt << 6, n0 = nt << 6;
    const int ra = t >> 2, ca = (t & 3) << 2;
    const size_t pst = (size_t)VV * VV;
    float4 a0 = {0,0,0,0}, a1 = {0,0,0,0}, a2 = {0,0,0,0}, a3 = {0,0,0,0};

    auto loadA = [&](int k0) -> float4 {
        if (mode == 0)
            return *(const float4*)(Agl + (size_t)(m0 + ra) * K + k0 + ca);
        const size_t off = (size_t)(m0 + ra) * VV + k0 + ca;
        float4 s = *(const float4*)(bias + k0 + ca);
        #pragma unroll
        for (int sx = 0; sx < KS; ++sx) {
            const float4 pv = *(const float4*)(prev + (size_t)sx * pst + off);
            s.x += pv.x; s.y += pv.y; s.z += pv.z; s.w += pv.w;
        }
        float4 av;
        if (mode == 1) {
            av.x = s.x / (1.f + __expf(-s.x));
            av.y = s.y / (1.f + __expf(-s.y));
            av.z = s.z / (1.f + __expf(-s.z));
            av.w = s.w / (1.f + __expf(-s.w));
        } else {
            const float4 h  = *(const float4*)(hc + (size_t)(m0 + ra) * (2 * VV) + k0 + ca);
            const float4 rr = *(const float4*)(hc + (size_t)(m0 + ra) * (2 * VV) + VV + k0 + ca);
            av.x = h.x + rr.x / (1.f + __expf(-s.x));
            av.y = h.y + rr.y / (1.f + __expf(-s.y));
            av.z = h.z + rr.z / (1.f + __expf(-s.z));
            av.w = h.w + rr.w / (1.f + __expf(-s.w));
        }
        return av;
    };

    {
        const float4 av = loadA(kbeg);
        const float4 wv = *(const float4*)(W + (size_t)(n0 + ra) * K + kbeg + ca);
        As[0][ca + 0][ra] = av.x; As[0][ca + 1][ra] = av.y;
        As[0][ca + 2][ra] = av.z; As[0][ca + 3][ra] = av.w;
        Bs[0][ca + 0][ra] = wv.x; Bs[0][ca + 1][ra] = wv.y;
        Bs[0][ca + 2][ra] = wv.z; Bs[0][ca + 3][ra] = wv.w;
    }
    __syncthreads();

    int cur = 0;
    for (int k0 = kbeg; k0 < kend; k0 += 16) {
        const int knext = k0 + 16;
        const bool has = (knext < kend);
        float4 av2, wv2;
        if (has) {
            av2 = loadA(knext);
            wv2 = *(const float4*)(W + (size_t)(n0 + ra) * K + knext + ca);
        }
        #pragma unroll
        for (int k = 0; k < 16; ++k) {
            const float4 a = *(const float4*)&As[cur][k][ty << 2];
            const float4 b = *(const float4*)&Bs[cur][k][tx << 2];
            a0.x += a.x * b.x; a0.y += a.x * b.y; a0.z += a.x * b.z; a0.w += a.x * b.w;
            a1.x += a.y * b.x; a1.y += a.y * b.y; a1.z += a.y * b.z; a1.w += a.y * b.w;
            a2.x += a.z * b.x; a2.y += a.z * b.y; a2.z += a.z * b.z; a2.w += a.z * b.w;
            a3.x += a.w * b.x; a3.y += a.w * b.y; a3.z += a.w * b.z; a3.w += a.w * b.w;
        }
        if (has) {
            const int nb = cur ^ 1;
            As[nb][ca + 0][ra] = av2.x; As[nb][ca + 1][ra] = av2.y;
            As[nb][ca + 2][ra] = av2.z; As[nb][ca + 3][ra] = av2.w;
            Bs[nb][ca + 0][ra] = wv2.x; Bs[nb][ca + 1][ra] = wv2.y;
            Bs[nb][ca + 2][ra] = wv2.z; Bs[nb][ca + 3][ra] = wv2.w;
        }
        __syncthreads();
        cur ^= 1;
    }

    if (mode == 2) {
        // atomicAdd partials into pre-biased out
        float* op = dst + (size_t)(m0 + (ty << 2)) * VV + n0 + (tx << 2);
        const float4 rws[4] = {a0, a1, a2, a3};
        #pragma unroll
        for (int r = 0; r < 4; ++r) {
            atomicAdd(op + r * VV + 0, rws[r].x);
            atomicAdd(op + r * VV + 1, rws[r].y);
            atomicAdd(op + r * VV + 2, rws[r].z);
            atomicAdd(op + r * VV + 3, rws[r].w);
        }
    } else {
        float* pp = dst + (size_t)ks * pst
                  + (size_t)(m0 + (ty << 2)) * VV + n0 + (tx << 2);
        *(float4*)(pp + 0 * VV) = a0;
        *(float4*)(pp + 1 * VV) = a1;
        *(float4*)(pp + 2 * VV) = a2;
        *(float4*)(pp + 3 * VV) = a3;
    }
}

extern "C" void kernel_launch(void* const* d_in, const int* in_sizes, int n_in,
                              void* d_out, int out_size, void* d_ws, size_t ws_size,
                              hipStream_t stream) {
    const float* keys    = (const float*)d_in[0];
    const float* values  = (const float*)d_in[1];
    const float* keyv    = (const float*)d_in[2];
    const float* valv    = (const float*)d_in[3];
    const float* hidden  = (const float*)d_in[4];
    const int*   wptr    = (const int*)d_in[5];
    const int*   filled  = (const int*)d_in[6];
    const float* Wq  = (const float*)d_in[7];
    const float* bq  = (const float*)d_in[8];
    const float* Wg1 = (const float*)d_in[9];
    const float* bg1 = (const float*)d_in[10];
    const float* Wg2 = (const float*)d_in[11];
    const float* bg2 = (const float*)d_in[12];
    const float* Wo  = (const float*)d_in[13];
    const float* bo  = (const float*)d_in[14];
    float* out = (float*)d_out;

    // workspace layout (floats)
    float* ws    = (float*)d_ws;
    float* q     = ws;                                  // 65536
    float* ml    = q + (size_t)BB * KK;                 // BB*NC*2 = 8192
    float* accp  = ml + (size_t)BB * NC * 2;            // BB*NC*VV = 2097152
    float* hcat  = accp + (size_t)BB * NC * VV;         // 524288
    float* part1 = hcat + (size_t)BB * 2 * VV;          // KS*VV*VV = 2097152
    float* part2 = part1 + (size_t)KS * VV * VV;        // 2097152

    q_kernel<<<BB / QB, 256, 0, stream>>>(hidden, Wq, bq, q);
    attn_chunk_kernel<<<BB * NC, 256, 0, stream>>>(keys, values, keyv, valv, q,
                                                   wptr, filled, ml, accp);
    combine_kernel<<<BB, 128, 0, stream>>>(hidden, ml, accp, hcat, bo, out);

    gemm_ks_kernel<<<64 * KS, 256, 0, stream>>>(hcat, 2 * VV, Wg1,
                                                nullptr, nullptr, nullptr,
                                                part1, 0);
    gemm_ks_kernel<<<64 * KS, 256, 0, stream>>>(nullptr, VV, Wg2,
                                                part1, bg1, nullptr,
                                                part2, 1);
    gemm_ks_kernel<<<64 * KS, 256, 0, stream>>>(nullptr, VV, Wo,
                                                part2, bg2, hcat,
                                                out, 2);
}

// Round 23
// 203.536 us; speedup vs baseline: 1.2310x; 1.2310x over previous
//
#include <hip/hip_runtime.h>
#include <math.h>

#define BB 512
#define SS 1024
#define KK 128
#define VV 512
#define NC 16     // s-chunks per batch (4x oversubscription)
#define CH 64     // rows per chunk
#define KS 8      // K-split for MLP GEMMs (512 blocks = 2 blocks/CU)
#define QB 8      // batches per q-block

static constexpr float INV_SCALE = 0.088388347648318447f; // 1/sqrt(128)

typedef float nfloat4 __attribute__((ext_vector_type(4)));

__device__ __forceinline__ float4 ntload(const float4* p) {
    nfloat4 v = __builtin_nontemporal_load((const nfloat4*)p);
    return make_float4(v.x, v.y, v.z, v.w);
}

// ---------------- query kernel: q = hidden @ Wq.T + bq (coalesced, staged) ---
__global__ __launch_bounds__(256) void q_kernel(
    const float* __restrict__ hidden, const float* __restrict__ Wq,
    const float* __restrict__ bq, float* __restrict__ qout)
{
    __shared__ float hidb[QB][516];
    __shared__ float wqt[16][516];
    __shared__ float qp[16][QB][2];
    const int blk = blockIdx.x;
    const int t = threadIdx.x;
    const int b0 = blk * QB;

    for (int i = t; i < QB * 128; i += 256) {
        const int bl = i >> 7, c4 = i & 127;
        *(float4*)&hidb[bl][c4 * 4] =
            ((const float4*)(hidden + (size_t)(b0 + bl) * VV))[c4];
    }
    for (int k0 = 0; k0 < KK; k0 += 16) {
        __syncthreads();
        for (int i = t; i < 16 * 128; i += 256) {
            const int kl = i >> 7, c4 = i & 127;
            *(float4*)&wqt[kl][c4 * 4] =
                ((const float4*)(Wq + (size_t)(k0 + kl) * VV))[c4];
        }
        __syncthreads();
        {
            const int p = t & 127, half = t >> 7;
            const int kl = p >> 3, bl = p & 7;
            const float* wr = &wqt[kl][half * 256];
            const float* hr = &hidb[bl][half * 256];
            float acc = 0.f;
            #pragma unroll
            for (int j = 0; j < 64; ++j) {
                const float4 wv = *(const float4*)&wr[j * 4];
                const float4 hv = *(const float4*)&hr[j * 4];
                acc += wv.x * hv.x + wv.y * hv.y + wv.z * hv.z + wv.w * hv.w;
            }
            qp[kl][bl][half] = acc;
        }
        __syncthreads();
        if (t < 128) {
            const int kl = t >> 3, bl = t & 7;
            qout[(size_t)(b0 + bl) * KK + k0 + kl] =
                qp[kl][bl][0] + qp[kl][bl][1] + bq[k0 + kl];
        }
    }
}

// ---------------- attention chunk (NC=16, CH=64, nt loads) -------------------
__global__ __launch_bounds__(256) void attn_chunk_kernel(
    const float* __restrict__ keys, const float* __restrict__ values,
    const float* __restrict__ keyv, const float* __restrict__ valv,
    const float* __restrict__ q,
    const int* __restrict__ write_ptr, const int* __restrict__ filled,
    float* __restrict__ ml, float* __restrict__ accp)
{
    __shared__ __align__(16) float qs[KK];
    __shared__ __align__(16) float p[CH];
    __shared__ __align__(16) float red[4];
    __shared__ __align__(16) float4 pvp[VV / 4];

    const int bc = blockIdx.x;
    const int b = bc >> 4;
    const int c = bc & 15;
    const int t = threadIdx.x;
    const int wave = t >> 6, lane = t & 63;

    int f = filled[b] + 1; if (f > SS) f = SS;
    const int sbeg = c * CH;
    int n = f - sbeg; if (n > CH) n = CH;

    float* mlrow = ml + ((size_t)b * NC + c) * 2;
    float* arow  = accp + ((size_t)b * NC + c) * VV;

    if (n <= 0) {
        if (t == 0) { mlrow[0] = -INFINITY; mlrow[1] = 0.f; }
        return;
    }

    if (t < KK / 4) ((float4*)qs)[t] = ((const float4*)(q + (size_t)b * KK))[t];
    __syncthreads();

    const int sub = lane & 31, rsel = lane >> 5;
    const int srow = wave * 2 + rsel;  // 0..7
    const float4 q4 = ((const float4*)qs)[sub];
    const float* kb = keys + ((size_t)b * SS + sbeg) * KK;
    const float* kw = keyv + (size_t)b * KK;
    const int wpl = write_ptr[b] - sbeg;

    const int nmain = n & ~31;
    for (int s0 = 0; s0 < nmain; s0 += 32) {
        float4 kv[4];
        #pragma unroll
        for (int u = 0; u < 4; ++u) {
            const int s = s0 + u * 8 + srow;
            const float* kr = (s == wpl) ? kw : (kb + (size_t)s * KK);
            kv[u] = ntload(((const float4*)kr) + sub);
        }
        #pragma unroll
        for (int u = 0; u < 4; ++u) {
            float prt = kv[u].x * q4.x + kv[u].y * q4.y
                      + kv[u].z * q4.z + kv[u].w * q4.w;
            prt += __shfl_xor(prt, 16);
            prt += __shfl_xor(prt, 8);
            prt += __shfl_xor(prt, 4);
            prt += __shfl_xor(prt, 2);
            prt += __shfl_xor(prt, 1);
            if (sub == 0) p[s0 + u * 8 + srow] = prt * INV_SCALE;
        }
    }
    for (int s = nmain + srow; s < n; s += 8) {
        const float* kr = (s == wpl) ? kw : (kb + (size_t)s * KK);
        const float4 kv = ntload(((const float4*)kr) + sub);
        float prt = kv.x * q4.x + kv.y * q4.y + kv.z * q4.z + kv.w * q4.w;
        prt += __shfl_xor(prt, 16);
        prt += __shfl_xor(prt, 8);
        prt += __shfl_xor(prt, 4);
        prt += __shfl_xor(prt, 2);
        prt += __shfl_xor(prt, 1);
        if (sub == 0) p[s] = prt * INV_SCALE;
    }
    __syncthreads();

    float lmax = -INFINITY;
    for (int i = t; i < n; i += 256) lmax = fmaxf(lmax, p[i]);
    lmax = fmaxf(lmax, __shfl_xor(lmax, 32));
    lmax = fmaxf(lmax, __shfl_xor(lmax, 16));
    lmax = fmaxf(lmax, __shfl_xor(lmax, 8));
    lmax = fmaxf(lmax, __shfl_xor(lmax, 4));
    lmax = fmaxf(lmax, __shfl_xor(lmax, 2));
    lmax = fmaxf(lmax, __shfl_xor(lmax, 1));
    if (lane == 0) red[wave] = lmax;
    __syncthreads();
    const float m = fmaxf(fmaxf(red[0], red[1]), fmaxf(red[2], red[3]));
    float lsum = 0.f;
    for (int i = t; i < n; i += 256) {
        const float e = __expf(p[i] - m);
        p[i] = e;
        lsum += e;
    }
    lsum += __shfl_xor(lsum, 32);
    lsum += __shfl_xor(lsum, 16);
    lsum += __shfl_xor(lsum, 8);
    lsum += __shfl_xor(lsum, 4);
    lsum += __shfl_xor(lsum, 2);
    lsum += __shfl_xor(lsum, 1);
    __syncthreads();
    if (lane == 0) red[wave] = lsum;
    __syncthreads();
    const float l = red[0] + red[1] + red[2] + red[3];

    const int col4 = t & 127, stream = t >> 7;
    const float4* vb = (const float4*)(values + ((size_t)b * SS + sbeg) * VV);
    const float4* vw = (const float4*)(valv + (size_t)b * VV);
    float4 acc = make_float4(0.f, 0.f, 0.f, 0.f);
    const int nm2 = n & ~15;
    for (int s0 = 0; s0 < nm2; s0 += 16) {
        float4 v[8]; float ps[8];
        #pragma unroll
        for (int u = 0; u < 8; ++u) {
            const int s = s0 + u * 2 + stream;
            const float4* vr = (s == wpl) ? vw : (vb + (size_t)s * (VV / 4));
            v[u] = ntload(vr + col4);
            ps[u] = p[s];
        }
        #pragma unroll
        for (int u = 0; u < 8; ++u) {
            acc.x += ps[u] * v[u].x;
            acc.y += ps[u] * v[u].y;
            acc.z += ps[u] * v[u].z;
            acc.w += ps[u] * v[u].w;
        }
    }
    for (int s = nm2 + stream; s < n; s += 2) {
        const float4* vr = (s == wpl) ? vw : (vb + (size_t)s * (VV / 4));
        const float4 v = ntload(vr + col4);
        const float psv = p[s];
        acc.x += psv * v.x;
        acc.y += psv * v.y;
        acc.z += psv * v.z;
        acc.w += psv * v.w;
    }
    if (stream == 1) pvp[col4] = acc;
    __syncthreads();
    if (stream == 0) {
        const float4 o = pvp[col4];
        ((float4*)arow)[col4] = make_float4(acc.x + o.x, acc.y + o.y,
                                            acc.z + o.z, acc.w + o.w);
    }
    if (t == 0) { mlrow[0] = m; mlrow[1] = l; }
}

// ---------------- combine chunk partials -> hcat = [hidden | retrieved] ------
__global__ __launch_bounds__(128) void combine_kernel(
    const float* __restrict__ hidden, const float* __restrict__ ml,
    const float* __restrict__ accp, float* __restrict__ hcat)
{
    const int b = blockIdx.x, t = threadIdx.x;
    const float* mlb = ml + (size_t)b * NC * 2;
    float mv[NC], lv[NC];
    #pragma unroll
    for (int c = 0; c < NC; ++c) { mv[c] = mlb[2 * c]; lv[c] = mlb[2 * c + 1]; }
    float ms = mv[0];
    #pragma unroll
    for (int c = 1; c < NC; ++c) ms = fmaxf(ms, mv[c]);
    float w[NC], denom = 0.f;
    #pragma unroll
    for (int c = 0; c < NC; ++c) { w[c] = __expf(mv[c] - ms); denom += w[c] * lv[c]; }
    const float invd = 1.f / denom;
    float4 r = make_float4(0.f, 0.f, 0.f, 0.f);
    for (int c = 0; c < NC; ++c) {
        if (lv[c] != 0.f) {
            const float4 x = ((const float4*)(accp + ((size_t)b * NC + c) * VV))[t];
            r.x += w[c] * x.x; r.y += w[c] * x.y;
            r.z += w[c] * x.z; r.w += w[c] * x.w;
        }
    }
    r.x *= invd; r.y *= invd; r.z *= invd; r.w *= invd;
    float4* hc = (float4*)(hcat + (size_t)b * 2 * VV);
    hc[t] = ((const float4*)(hidden + (size_t)b * VV))[t];
    hc[VV / 4 + t] = r;
}

// ---------------- K-split GEMM, double-buffered LDS staging ------------------
// part[ks] = A_eff[:,kseg] @ W^T[kseg,:]; W row-major [512][K], transposed
// during staging. Tile 64x64, 4x4 micro, BK=16, grid = 64 x KS = 512 blocks.
// mode 0: A_eff = Agl (hcat)
// mode 1: A_eff = silu(sum_KS prev + bias)
// mode 2: A_eff = hc[:, :512] + hc[:, 512:] * sigmoid(sum_KS prev + bias)
__global__ __launch_bounds__(256) void gemm_ks_kernel(
    const float* __restrict__ Agl, int K, const float* __restrict__ W,
    const float* __restrict__ prev, const float* __restrict__ bias,
    const float* __restrict__ hc, float* __restrict__ part, int mode)
{
    __shared__ __align__(16) float As[2][16][68];
    __shared__ __align__(16) float Bs[2][16][68];
    const int bx = blockIdx.x;
    const int mt = bx & 7, nt = (bx >> 3) & 7, ks = bx >> 6;
    const int kseg = K >> 3;               // K / KS
    const int kbeg = ks * kseg, kend = kbeg + kseg;
    const int t = threadIdx.x;
    const int tx = t & 15, ty = t >> 4;
    const int m0 = mt << 6, n0 = nt << 6;
    const int ra = t >> 2, ca = (t & 3) << 2;
    const size_t pst = (size_t)VV * VV;
    float4 a0 = {0,0,0,0}, a1 = {0,0,0,0}, a2 = {0,0,0,0}, a3 = {0,0,0,0};

    auto loadA = [&](int k0) -> float4 {
        if (mode == 0)
            return *(const float4*)(Agl + (size_t)(m0 + ra) * K + k0 + ca);
        const size_t off = (size_t)(m0 + ra) * VV + k0 + ca;
        float4 s = *(const float4*)(bias + k0 + ca);
        #pragma unroll
        for (int sx = 0; sx < KS; ++sx) {
            const float4 pv = *(const float4*)(prev + (size_t)sx * pst + off);
            s.x += pv.x; s.y += pv.y; s.z += pv.z; s.w += pv.w;
        }
        float4 av;
        if (mode == 1) {
            av.x = s.x / (1.f + __expf(-s.x));
            av.y = s.y / (1.f + __expf(-s.y));
            av.z = s.z / (1.f + __expf(-s.z));
            av.w = s.w / (1.f + __expf(-s.w));
        } else {
            const float4 h  = *(const float4*)(hc + (size_t)(m0 + ra) * (2 * VV) + k0 + ca);
            const float4 rr = *(const float4*)(hc + (size_t)(m0 + ra) * (2 * VV) + VV + k0 + ca);
            av.x = h.x + rr.x / (1.f + __expf(-s.x));
            av.y = h.y + rr.y / (1.f + __expf(-s.y));
            av.z = h.z + rr.z / (1.f + __expf(-s.z));
            av.w = h.w + rr.w / (1.f + __expf(-s.w));
        }
        return av;
    };

    // prologue: stage first tile into buffer 0
    {
        const float4 av = loadA(kbeg);
        const float4 wv = *(const float4*)(W + (size_t)(n0 + ra) * K + kbeg + ca);
        As[0][ca + 0][ra] = av.x; As[0][ca + 1][ra] = av.y;
        As[0][ca + 2][ra] = av.z; As[0][ca + 3][ra] = av.w;
        Bs[0][ca + 0][ra] = wv.x; Bs[0][ca + 1][ra] = wv.y;
        Bs[0][ca + 2][ra] = wv.z; Bs[0][ca + 3][ra] = wv.w;
    }
    __syncthreads();

    int cur = 0;
    for (int k0 = kbeg; k0 < kend; k0 += 16) {
        const int knext = k0 + 16;
        const bool has = (knext < kend);
        float4 av2, wv2;
        if (has) {   // issue next-tile loads BEFORE compute (latency hidden)
            av2 = loadA(knext);
            wv2 = *(const float4*)(W + (size_t)(n0 + ra) * K + knext + ca);
        }
        #pragma unroll
        for (int k = 0; k < 16; ++k) {
            const float4 a = *(const float4*)&As[cur][k][ty << 2];
            const float4 b = *(const float4*)&Bs[cur][k][tx << 2];
            a0.x += a.x * b.x; a0.y += a.x * b.y; a0.z += a.x * b.z; a0.w += a.x * b.w;
            a1.x += a.y * b.x; a1.y += a.y * b.y; a1.z += a.y * b.z; a1.w += a.y * b.w;
            a2.x += a.z * b.x; a2.y += a.z * b.y; a2.z += a.z * b.z; a2.w += a.z * b.w;
            a3.x += a.w * b.x; a3.y += a.w * b.y; a3.z += a.w * b.z; a3.w += a.w * b.w;
        }
        if (has) {
            const int nb = cur ^ 1;
            As[nb][ca + 0][ra] = av2.x; As[nb][ca + 1][ra] = av2.y;
            As[nb][ca + 2][ra] = av2.z; As[nb][ca + 3][ra] = av2.w;
            Bs[nb][ca + 0][ra] = wv2.x; Bs[nb][ca + 1][ra] = wv2.y;
            Bs[nb][ca + 2][ra] = wv2.z; Bs[nb][ca + 3][ra] = wv2.w;
        }
        __syncthreads();
        cur ^= 1;
    }

    float* pp = part + (size_t)ks * pst
              + (size_t)(m0 + (ty << 2)) * VV + n0 + (tx << 2);
    *(float4*)(pp + 0 * VV) = a0;
    *(float4*)(pp + 1 * VV) = a1;
    *(float4*)(pp + 2 * VV) = a2;
    *(float4*)(pp + 3 * VV) = a3;
}

// ---------------- final reduce: out = sum_ks part3 + bo ----------------------
__global__ __launch_bounds__(128) void reduce_bias_kernel(
    const float* __restrict__ part, const float* __restrict__ bo,
    float* __restrict__ out)
{
    const int b = blockIdx.x, t = threadIdx.x;
    const size_t o = (size_t)b * (VV / 4) + t;
    const size_t st = (size_t)VV * (VV / 4);
    const float4* p4 = (const float4*)part;
    const float4 bb = ((const float4*)bo)[t];
    float4 s = bb;
    #pragma unroll
    for (int k = 0; k < KS; ++k) {
        const float4 pv = p4[o + (size_t)k * st];
        s.x += pv.x; s.y += pv.y; s.z += pv.z; s.w += pv.w;
    }
    ((float4*)out)[o] = s;
}

extern "C" void kernel_launch(void* const* d_in, const int* in_sizes, int n_in,
                              void* d_out, int out_size, void* d_ws, size_t ws_size,
                              hipStream_t stream) {
    const float* keys    = (const float*)d_in[0];
    const float* values  = (const float*)d_in[1];
    const float* keyv    = (const float*)d_in[2];
    const float* valv    = (const float*)d_in[3];
    const float* hidden  = (const float*)d_in[4];
    const int*   wptr    = (const int*)d_in[5];
    const int*   filled  = (const int*)d_in[6];
    const float* Wq  = (const float*)d_in[7];
    const float* bq  = (const float*)d_in[8];
    const float* Wg1 = (const float*)d_in[9];
    const float* bg1 = (const float*)d_in[10];
    const float* Wg2 = (const float*)d_in[11];
    const float* bg2 = (const float*)d_in[12];
    const float* Wo  = (const float*)d_in[13];
    const float* bo  = (const float*)d_in[14];
    float* out = (float*)d_out;

    // workspace layout (floats)
    float* ws    = (float*)d_ws;
    float* q     = ws;                                  // 65536
    float* ml    = q + (size_t)BB * KK;                 // BB*NC*2 = 16384
    float* accp  = ml + (size_t)BB * NC * 2;            // BB*NC*VV = 4194304
    float* hcat  = accp + (size_t)BB * NC * VV;         // 524288
    float* part1 = hcat + (size_t)BB * 2 * VV;          // KS*VV*VV = 2097152
    float* part2 = part1 + (size_t)KS * VV * VV;        // 2097152
    float* part3 = part2 + (size_t)KS * VV * VV;        // 2097152

    q_kernel<<<BB / QB, 256, 0, stream>>>(hidden, Wq, bq, q);
    attn_chunk_kernel<<<BB * NC, 256, 0, stream>>>(keys, values, keyv, valv, q,
                                                   wptr, filled, ml, accp);
    combine_kernel<<<BB, 128, 0, stream>>>(hidden, ml, accp, hcat);

    gemm_ks_kernel<<<64 * KS, 256, 0, stream>>>(hcat, 2 * VV, Wg1,
                                                nullptr, nullptr, nullptr,
                                                part1, 0);
    gemm_ks_kernel<<<64 * KS, 256, 0, stream>>>(nullptr, VV, Wg2,
                                                part1, bg1, nullptr,
                                                part2, 1);
    gemm_ks_kernel<<<64 * KS, 256, 0, stream>>>(nullptr, VV, Wo,
                                                part2, bg2, hcat,
                                                part3, 2);
    reduce_bias_kernel<<<BB, 128, 0, stream>>>(part3, bo, out);
}